// Round 2
// baseline (737.540 us; speedup 1.0000x reference)
//
#include <hip/hip_runtime.h>
#include <hip/hip_fp16.h>

#define NUM_USERS 100000
#define NUM_ITEMS 50000
#define EMBED_DIM 64
#define N_NODES 150000
#define N_EDGES 4000000
#define N_LAYERS 3
#define BATCH 1024

#define NBKT 293            // buckets of 512 nodes: src >> 9
#define CHUNK 8192
#define NBLK_A ((N_EDGES + CHUNK - 1) / CHUNK)   // 489

#define NSLICE 10           // dst slice = dst >> 14 (2 MB fp16 table per slice)
#define NKEY (512 * 16)     // passB key = local(9b)<<4 | slice(4b)

#define GBLK 1024           // resident gather grid: 4 blocks/CU
#define NGRP (GBLK * 32)    // 8-lane groups total = 32768
#define NPT 5               // nodes per group (5*32768 >= 150000)

typedef float f32x4 __attribute__((ext_vector_type(4)));
typedef _Float16 f16x8 __attribute__((ext_vector_type(8)));
typedef float f32x4a __attribute__((ext_vector_type(4)));

// clear + mark batch users
__global__ void clear_uflag_kernel(int* __restrict__ uflag) {
    int i = blockIdx.x * blockDim.x + threadIdx.x;
    if (i < NUM_USERS) uflag[i] = 0;
}

__global__ void mark_users_kernel(const int* __restrict__ users, int* __restrict__ uflag) {
    int i = blockIdx.x * blockDim.x + threadIdx.x;
    if (i < BATCH) uflag[users[i]] = 1;
}

// ---------------- init: fp16 table (all) + acc fp32 (needed rows only) -------
__global__ void init_emb_kernel(const float* __restrict__ ue, const float* __restrict__ ie,
                                const int* __restrict__ uflag,
                                float* __restrict__ acc, __half2* __restrict__ h0) {
    int i = blockIdx.x * blockDim.x + threadIdx.x;           // float4 index
    const int total  = N_NODES * (EMBED_DIM / 4);
    const int usplit = NUM_USERS * (EMBED_DIM / 4);
    if (i < total) {
        float4 v = (i < usplit) ? reinterpret_cast<const float4*>(ue)[i]
                                : reinterpret_cast<const float4*>(ie)[i - usplit];
        h0[i * 2 + 0] = __float22half2_rn(make_float2(v.x, v.y));
        h0[i * 2 + 1] = __float22half2_rn(make_float2(v.z, v.w));
        int n = i >> 4;
        if (n >= NUM_USERS || uflag[n])
            reinterpret_cast<float4*>(acc)[i] = v;
    }
}

// ---------------- CSR build: two-level LDS counting sort (NO global atomics) -
__global__ void histA_kernel(const int* __restrict__ src, int* __restrict__ hist) {
    __shared__ int lcnt[NBKT];
    int blk = blockIdx.x, t = threadIdx.x;
    for (int b = t; b < NBKT; b += 256) lcnt[b] = 0;
    __syncthreads();
    int e0 = blk * CHUNK;
    for (int i = t; i < CHUNK; i += 256) {
        int e = e0 + i;
        if (e < N_EDGES) atomicAdd(&lcnt[src[e] >> 9], 1);
    }
    __syncthreads();
    for (int b = t; b < NBKT; b += 256) hist[blk * NBKT + b] = lcnt[b];
}

__global__ void scanA_kernel(const int* __restrict__ hist, int* __restrict__ off,
                             int* __restrict__ bucketTotal) {
    __shared__ int s[512];
    int b = blockIdx.x, t = threadIdx.x;         // 512 threads
    int v0 = (t < NBLK_A) ? hist[t * NBKT + b] : 0;
    s[t] = v0;
    __syncthreads();
    for (int o = 1; o < 512; o <<= 1) {
        int v = (t >= o) ? s[t - o] : 0;
        __syncthreads();
        s[t] += v;
        __syncthreads();
    }
    if (t < NBLK_A) off[t * NBKT + b] = s[t] - v0;   // exclusive
    if (t == NBLK_A - 1) bucketTotal[b] = s[t];
}

__global__ void scanB_kernel(const int* __restrict__ bucketTotal, int* __restrict__ bucketBase,
                             int* __restrict__ rowptr) {
    __shared__ int s[512];
    int t = threadIdx.x;                         // 512 threads
    s[t] = (t < NBKT) ? bucketTotal[t] : 0;
    __syncthreads();
    for (int o = 1; o < 512; o <<= 1) {
        int v = (t >= o) ? s[t - o] : 0;
        __syncthreads();
        s[t] += v;
        __syncthreads();
    }
    if (t < NBKT) bucketBase[t] = (t > 0) ? s[t - 1] : 0;
    if (t == 0) { bucketBase[NBKT] = s[NBKT - 1]; rowptr[N_NODES] = N_EDGES; }
}

// A3: partition edges to bucket segments. tmp = (local_src, dst|q14<<18)
// val quantized to 14-bit fixed point (val in [0,1); err 3e-5 << fp16 table err)
__global__ void partA3_kernel(const int* __restrict__ src, const int* __restrict__ dst,
                              const float* __restrict__ val, const int* __restrict__ off,
                              const int* __restrict__ bucketBase, int2* __restrict__ tmp) {
    __shared__ int lcnt[NBKT];
    int blk = blockIdx.x, t = threadIdx.x;
    for (int b = t; b < NBKT; b += 256) lcnt[b] = 0;
    __syncthreads();
    int e0 = blk * CHUNK;
    for (int i = t; i < CHUNK; i += 256) {
        int e = e0 + i;
        if (e < N_EDGES) {
            int s = src[e];
            int b = s >> 9;
            int r = atomicAdd(&lcnt[b], 1);
            int pos = bucketBase[b] + off[blk * NBKT + b] + r;
            int q = (int)(val[e] * 16384.0f);
            if (q > 16383) q = 16383;
            tmp[pos] = make_int2(s & 511, dst[e] | (q << 18));
        }
    }
}

// B: per bucket: counting sort by key = local(9b)<<4 | dst_slice(4b).
// Produces per-row edge lists SORTED BY DST SLICE (the gather locality key),
// and 4-byte edge records (dst | q14).
__global__ __launch_bounds__(512)
void passB_kernel(const int2* __restrict__ tmp, const int* __restrict__ bucketBase,
                  int* __restrict__ rowptr, unsigned* __restrict__ edge_s) {
    __shared__ int sdeg[NKEY];   // 32 KB
    __shared__ int cur[NKEY];    // 32 KB
    __shared__ int ttot[512];
    int bkt = blockIdx.x;
    int t = threadIdx.x;                         // 512 threads
    int base = bucketBase[bkt];
    int cntE = bucketBase[bkt + 1] - base;
    for (int k = t; k < NKEY; k += 512) sdeg[k] = 0;
    __syncthreads();
    for (int i = t; i < cntE; i += 512) {
        int2 e = tmp[base + i];
        int key = (e.x << 4) | ((e.y & 0x3FFFF) >> 14);
        atomicAdd(&sdeg[key], 1);
    }
    __syncthreads();
    // exclusive scan over 8192 keys: 16 serial per thread + scan of totals
    int run = 0;
    int k0 = t * 16;
#pragma unroll
    for (int i = 0; i < 16; ++i) { int v = sdeg[k0 + i]; sdeg[k0 + i] = run; run += v; }
    ttot[t] = run;
    __syncthreads();
    for (int o = 1; o < 512; o <<= 1) {          // inclusive Hillis-Steele
        int v = (t >= o) ? ttot[t - o] : 0;
        __syncthreads();
        ttot[t] += v;
        __syncthreads();
    }
    int texcl = ttot[t] - run;                   // exclusive prefix at key t*16
#pragma unroll
    for (int i = 0; i < 16; ++i) { int v = sdeg[k0 + i] + texcl; sdeg[k0 + i] = v; cur[k0 + i] = v; }
    int n = (bkt << 9) + t;                      // node local = t, slice 0 start
    if (n < N_NODES) rowptr[n] = base + texcl;
    __syncthreads();
    for (int i = t; i < cntE; i += 512) {
        int2 e = tmp[base + i];
        int key = (e.x << 4) | ((e.y & 0x3FFFF) >> 14);
        int p = base + atomicAdd(&cur[key], 1);
        edge_s[p] = (unsigned)e.y;
    }
}

// ---------------- propagation layer: resident grid, slice-synchronized -------
// Each 8-lane group owns NPT nodes (acc in registers). Outer loop walks the 10
// dst-slices with a block sync per slice -> device-wide soft lockstep -> the
// 2 MB table slice being gathered is L2-resident on every XCD.
template <bool WRITE_NXT>
__global__ __launch_bounds__(256, 4)
void gather_layer_kernel(const __half* __restrict__ emb, const int* __restrict__ rowptr,
                         const unsigned* __restrict__ eg, const int* __restrict__ uflag,
                         __half* __restrict__ outp, float* __restrict__ acc) {
    const int t = threadIdx.x;
    const int g = blockIdx.x * 32 + (t >> 3);    // group id 0..32767
    const int c = (t & 7) * 8;                   // dim offset (8 dims/lane)

    float a[NPT][8];
    int jc[NPT], je[NPT];
    bool nd[NPT];
#pragma unroll
    for (int q = 0; q < NPT; ++q) {
        int n = q * NGRP + g;
        bool ok = n < N_NODES;
        bool need = ok && ((n >= NUM_USERS) || uflag[n]);
        nd[q] = need;
        int beg = 0, end = 0;
        if (ok && (WRITE_NXT || need)) { beg = rowptr[n]; end = rowptr[n + 1]; }
        jc[q] = beg; je[q] = end;
#pragma unroll
        for (int i = 0; i < 8; ++i) a[q][i] = 0.f;
    }

    for (int sl = 0; sl < NSLICE; ++sl) {
        int hi = (sl + 1) << 14;                 // consume edges with dst < hi
#pragma unroll
        for (int q = 0; q < NPT; ++q) {
            int j = jc[q], e2 = je[q];
            while (j < e2) {
                unsigned ew = eg[j];
                int d = ew & 0x3FFFF;
                if (d >= hi) break;
                float v = ((float)(ew >> 18) + 0.5f) * 6.103515625e-5f;
                uint4 r = *reinterpret_cast<const uint4*>(emb + (long)d * EMBED_DIM + c);
                const __half2* hp = reinterpret_cast<const __half2*>(&r);
                float2 f0 = __half22float2(hp[0]); float2 f1 = __half22float2(hp[1]);
                float2 f2 = __half22float2(hp[2]); float2 f3 = __half22float2(hp[3]);
                a[q][0] += f0.x * v; a[q][1] += f0.y * v; a[q][2] += f1.x * v; a[q][3] += f1.y * v;
                a[q][4] += f2.x * v; a[q][5] += f2.y * v; a[q][6] += f3.x * v; a[q][7] += f3.y * v;
                ++j;
            }
            jc[q] = j;
        }
        __syncthreads();                         // slice lockstep (perf only)
    }

#pragma unroll
    for (int q = 0; q < NPT; ++q) {
        int n = q * NGRP + g;
        if (n >= N_NODES) continue;
        if (WRITE_NXT) {
            uint4 o;
            __half2* op = reinterpret_cast<__half2*>(&o);
            op[0] = __float22half2_rn(make_float2(a[q][0], a[q][1]));
            op[1] = __float22half2_rn(make_float2(a[q][2], a[q][3]));
            op[2] = __float22half2_rn(make_float2(a[q][4], a[q][5]));
            op[3] = __float22half2_rn(make_float2(a[q][6], a[q][7]));
            *reinterpret_cast<uint4*>(outp + (long)n * EMBED_DIM + c) = o;
            if (nd[q]) {
                float* ap = acc + (long)n * EMBED_DIM + c;
                float4 x0 = *reinterpret_cast<float4*>(ap);
                float4 x1 = *reinterpret_cast<float4*>(ap + 4);
                x0.x += a[q][0]; x0.y += a[q][1]; x0.z += a[q][2]; x0.w += a[q][3];
                x1.x += a[q][4]; x1.y += a[q][5]; x1.z += a[q][6]; x1.w += a[q][7];
                *reinterpret_cast<float4*>(ap)     = x0;
                *reinterpret_cast<float4*>(ap + 4) = x1;
            }
        } else if (nd[q]) {
            // final layer: acc + a is the FINAL value -> write fp16 T16 row
            const float* ap = acc + (long)n * EMBED_DIM + c;
            float4 x0 = *reinterpret_cast<const float4*>(ap);
            float4 x1 = *reinterpret_cast<const float4*>(ap + 4);
            uint4 o;
            __half2* op = reinterpret_cast<__half2*>(&o);
            op[0] = __float22half2_rn(make_float2(x0.x + a[q][0], x0.y + a[q][1]));
            op[1] = __float22half2_rn(make_float2(x0.z + a[q][2], x0.w + a[q][3]));
            op[2] = __float22half2_rn(make_float2(x1.x + a[q][4], x1.y + a[q][5]));
            op[3] = __float22half2_rn(make_float2(x1.z + a[q][6], x1.w + a[q][7]));
            *reinterpret_cast<uint4*>(outp + (long)n * EMBED_DIM + c) = o;
        }
    }
}

// ---------------- ratings: fp16 MFMA GEMM (fp32 accumulate) ------------------
// A rows gathered from node-indexed T16 via users[]; B rows = T16 item rows.
__global__ __launch_bounds__(256)
void ratings_mfma_kernel(const __half* __restrict__ T16, const int* __restrict__ users,
                         float* __restrict__ out) {
    const int w  = threadIdx.x >> 6;            // wave 0..3
    const int l  = threadIdx.x & 63;
    const int u0 = blockIdx.y * 32 + (w & 1) * 16;
    const int i0 = blockIdx.x * 128 + (w >> 1) * 64;
    const int row = l & 15;
    const int kq  = (l >> 4) * 8;
    const int uid = users[u0 + row];

    f32x4a acc0 = {0.f, 0.f, 0.f, 0.f};
    f32x4a acc1 = {0.f, 0.f, 0.f, 0.f};
    f32x4a acc2 = {0.f, 0.f, 0.f, 0.f};
    f32x4a acc3 = {0.f, 0.f, 0.f, 0.f};

    int ir0 = i0 + 0 * 16 + row; if (ir0 >= NUM_ITEMS) ir0 = NUM_ITEMS - 1;
    int ir1 = i0 + 1 * 16 + row; if (ir1 >= NUM_ITEMS) ir1 = NUM_ITEMS - 1;
    int ir2 = i0 + 2 * 16 + row; if (ir2 >= NUM_ITEMS) ir2 = NUM_ITEMS - 1;
    int ir3 = i0 + 3 * 16 + row; if (ir3 >= NUM_ITEMS) ir3 = NUM_ITEMS - 1;

#pragma unroll
    for (int ks = 0; ks < EMBED_DIM; ks += 32) {
        f16x8 a = *reinterpret_cast<const f16x8*>(T16 + (long)uid * EMBED_DIM + ks + kq);
        f16x8 b0 = *reinterpret_cast<const f16x8*>(T16 + (long)(NUM_USERS + ir0) * EMBED_DIM + ks + kq);
        f16x8 b1 = *reinterpret_cast<const f16x8*>(T16 + (long)(NUM_USERS + ir1) * EMBED_DIM + ks + kq);
        f16x8 b2 = *reinterpret_cast<const f16x8*>(T16 + (long)(NUM_USERS + ir2) * EMBED_DIM + ks + kq);
        f16x8 b3 = *reinterpret_cast<const f16x8*>(T16 + (long)(NUM_USERS + ir3) * EMBED_DIM + ks + kq);
        acc0 = __builtin_amdgcn_mfma_f32_16x16x32_f16(a, b0, acc0, 0, 0, 0);
        acc1 = __builtin_amdgcn_mfma_f32_16x16x32_f16(a, b1, acc1, 0, 0, 0);
        acc2 = __builtin_amdgcn_mfma_f32_16x16x32_f16(a, b2, acc2, 0, 0, 0);
        acc3 = __builtin_amdgcn_mfma_f32_16x16x32_f16(a, b3, acc3, 0, 0, 0);
    }

    const float inv = 1.0f / 16.0f;              // (acc/4)·(acc/4) = acc·acc/16
    const int orow = u0 + (l >> 4) * 4;
    const int colb = l & 15;
#define STORE_FRAG(ACC, C)                                                      \
    {                                                                           \
        int col = i0 + (C) * 16 + colb;                                         \
        if (col < NUM_ITEMS) {                                                  \
            __builtin_nontemporal_store(ACC[0] * inv, out + (long)(orow + 0) * NUM_ITEMS + col); \
            __builtin_nontemporal_store(ACC[1] * inv, out + (long)(orow + 1) * NUM_ITEMS + col); \
            __builtin_nontemporal_store(ACC[2] * inv, out + (long)(orow + 2) * NUM_ITEMS + col); \
            __builtin_nontemporal_store(ACC[3] * inv, out + (long)(orow + 3) * NUM_ITEMS + col); \
        }                                                                       \
    }
    STORE_FRAG(acc0, 0)
    STORE_FRAG(acc1, 1)
    STORE_FRAG(acc2, 2)
    STORE_FRAG(acc3, 3)
#undef STORE_FRAG
}

extern "C" void kernel_launch(void* const* d_in, const int* in_sizes, int n_in,
                              void* d_out, int out_size, void* d_ws, size_t ws_size,
                              hipStream_t stream) {
    const float* ue    = (const float*)d_in[0];
    const float* ie    = (const float*)d_in[1];
    const float* val   = (const float*)d_in[2];
    const int*   src   = (const int*)d_in[3];
    const int*   dst   = (const int*)d_in[4];
    const int*   users = (const int*)d_in[5];
    float* out = (float*)d_out;

    // ws: acc fp32 (38.4 MB) + two fp16 tables (19.2 MB each) + uflag (400 KB)
    const size_t tab = (size_t)N_NODES * EMBED_DIM;
    float*  acc   = (float*)d_ws;
    __half* h0    = (__half*)(acc + tab);
    __half* h1    = h0 + tab;
    int*    uflag = (int*)(h1 + tab);

    // CSR scratch lives in d_out (ratings overwrites all of it at the end)
    char* ob = (char*)d_out;
    unsigned* edge_s  = (unsigned*)(ob);                 // [0,16MB)  final 4B edges
    int2* tmp         = (int2*)(ob + (64u << 20));       // [64,96MB) bucket-partitioned
    int*  hist        = (int*) (ob + (96u << 20));       // 489*293*4 = 573 KB
    int*  off         = (int*) (ob + (98u << 20));       // 573 KB
    int*  bucketTotal = (int*) (ob + (100u << 20));      // 1.2 KB
    int*  bucketBase  = (int*) (ob + (101u << 20));      // 1.2 KB
    int*  rowptr      = (int*) (ob + (102u << 20));      // 600 KB + 4

    clear_uflag_kernel<<<(NUM_USERS + 255) / 256, 256, 0, stream>>>(uflag);
    mark_users_kernel<<<(BATCH + 255) / 256, 256, 0, stream>>>(users, uflag);

    const int totalv = N_NODES * EMBED_DIM / 4;
    init_emb_kernel<<<(totalv + 255) / 256, 256, 0, stream>>>(ue, ie, uflag, acc, (__half2*)h0);

    // ---- CSR build: LDS counting sort, slice-sorted rows, 4B edge records ----
    histA_kernel <<<NBLK_A, 256, 0, stream>>>(src, hist);
    scanA_kernel <<<NBKT, 512, 0, stream>>>(hist, off, bucketTotal);
    scanB_kernel <<<1, 512, 0, stream>>>(bucketTotal, bucketBase, rowptr);
    partA3_kernel<<<NBLK_A, 256, 0, stream>>>(src, dst, val, off, bucketBase, tmp);
    passB_kernel <<<NBKT, 512, 0, stream>>>(tmp, bucketBase, rowptr, edge_s);

    // ---- 3 propagation layers (slice-synchronized resident gather) ----
    gather_layer_kernel<true ><<<GBLK, 256, 0, stream>>>(h0, rowptr, edge_s, uflag, h1, acc);
    gather_layer_kernel<true ><<<GBLK, 256, 0, stream>>>(h1, rowptr, edge_s, uflag, h0, acc);
    gather_layer_kernel<false><<<GBLK, 256, 0, stream>>>(h0, rowptr, edge_s, uflag, h1, acc);

    // ---- ratings GEMM straight from T16 (= h1, written by layer 3) ----
    dim3 rgrid((NUM_ITEMS + 127) / 128, BATCH / 32);
    ratings_mfma_kernel<<<rgrid, 256, 0, stream>>>(h1, users, out);
}

// Round 3
// 370.155 us; speedup vs baseline: 1.9925x; 1.9925x over previous
//
#include <hip/hip_runtime.h>
#include <hip/hip_fp16.h>

#define NUM_USERS 100000
#define NUM_ITEMS 50000
#define EMBED_DIM 64
#define N_NODES 150000
#define N_EDGES 4000000
#define N_LAYERS 3
#define BATCH 1024

#define NBKT 293            // buckets of 512 nodes: src >> 9
#define CHUNK 8192
#define NBLK_A ((N_EDGES + CHUNK - 1) / CHUNK)   // 489

#define NSLICE 10           // dst slice = dst >> 14 (2 MB fp16 table per slice)
#define NKEY (512 * 16)     // passB key = local(9b)<<4 | slice(4b)

typedef float f32x4 __attribute__((ext_vector_type(4)));
typedef _Float16 f16x8 __attribute__((ext_vector_type(8)));
typedef float f32x4a __attribute__((ext_vector_type(4)));

// clear + mark batch users
__global__ void clear_uflag_kernel(int* __restrict__ uflag) {
    int i = blockIdx.x * blockDim.x + threadIdx.x;
    if (i < NUM_USERS) uflag[i] = 0;
}

__global__ void mark_users_kernel(const int* __restrict__ users, int* __restrict__ uflag) {
    int i = blockIdx.x * blockDim.x + threadIdx.x;
    if (i < BATCH) uflag[users[i]] = 1;
}

// ---------------- init: fp16 table (all) + acc fp32 (needed rows only) -------
__global__ void init_emb_kernel(const float* __restrict__ ue, const float* __restrict__ ie,
                                const int* __restrict__ uflag,
                                float* __restrict__ acc, __half2* __restrict__ h0) {
    int i = blockIdx.x * blockDim.x + threadIdx.x;           // float4 index
    const int total  = N_NODES * (EMBED_DIM / 4);
    const int usplit = NUM_USERS * (EMBED_DIM / 4);
    if (i < total) {
        float4 v = (i < usplit) ? reinterpret_cast<const float4*>(ue)[i]
                                : reinterpret_cast<const float4*>(ie)[i - usplit];
        h0[i * 2 + 0] = __float22half2_rn(make_float2(v.x, v.y));
        h0[i * 2 + 1] = __float22half2_rn(make_float2(v.z, v.w));
        int n = i >> 4;
        if (n >= NUM_USERS || uflag[n])
            reinterpret_cast<float4*>(acc)[i] = v;
    }
}

// ---------------- CSR build: two-level LDS counting sort (NO global atomics) -
__global__ void histA_kernel(const int* __restrict__ src, int* __restrict__ hist) {
    __shared__ int lcnt[NBKT];
    int blk = blockIdx.x, t = threadIdx.x;
    for (int b = t; b < NBKT; b += 256) lcnt[b] = 0;
    __syncthreads();
    int e0 = blk * CHUNK;
    for (int i = t; i < CHUNK; i += 256) {
        int e = e0 + i;
        if (e < N_EDGES) atomicAdd(&lcnt[src[e] >> 9], 1);
    }
    __syncthreads();
    for (int b = t; b < NBKT; b += 256) hist[blk * NBKT + b] = lcnt[b];
}

__global__ void scanA_kernel(const int* __restrict__ hist, int* __restrict__ off,
                             int* __restrict__ bucketTotal) {
    __shared__ int s[512];
    int b = blockIdx.x, t = threadIdx.x;         // 512 threads
    int v0 = (t < NBLK_A) ? hist[t * NBKT + b] : 0;
    s[t] = v0;
    __syncthreads();
    for (int o = 1; o < 512; o <<= 1) {
        int v = (t >= o) ? s[t - o] : 0;
        __syncthreads();
        s[t] += v;
        __syncthreads();
    }
    if (t < NBLK_A) off[t * NBKT + b] = s[t] - v0;   // exclusive
    if (t == NBLK_A - 1) bucketTotal[b] = s[t];
}

__global__ void scanB_kernel(const int* __restrict__ bucketTotal, int* __restrict__ bucketBase,
                             int* __restrict__ rowptr) {
    __shared__ int s[512];
    int t = threadIdx.x;                         // 512 threads
    s[t] = (t < NBKT) ? bucketTotal[t] : 0;
    __syncthreads();
    for (int o = 1; o < 512; o <<= 1) {
        int v = (t >= o) ? s[t - o] : 0;
        __syncthreads();
        s[t] += v;
        __syncthreads();
    }
    if (t < NBKT) bucketBase[t] = (t > 0) ? s[t - 1] : 0;
    if (t == 0) { bucketBase[NBKT] = s[NBKT - 1]; rowptr[N_NODES] = N_EDGES; }
}

// A3: partition edges to bucket segments. tmp = (local_src, dst|q14<<18)
// val quantized to 14-bit fixed point (val in [0,1); err 3e-5 << fp16 table err)
__global__ void partA3_kernel(const int* __restrict__ src, const int* __restrict__ dst,
                              const float* __restrict__ val, const int* __restrict__ off,
                              const int* __restrict__ bucketBase, int2* __restrict__ tmp) {
    __shared__ int lcnt[NBKT];
    int blk = blockIdx.x, t = threadIdx.x;
    for (int b = t; b < NBKT; b += 256) lcnt[b] = 0;
    __syncthreads();
    int e0 = blk * CHUNK;
    for (int i = t; i < CHUNK; i += 256) {
        int e = e0 + i;
        if (e < N_EDGES) {
            int s = src[e];
            int b = s >> 9;
            int r = atomicAdd(&lcnt[b], 1);
            int pos = bucketBase[b] + off[blk * NBKT + b] + r;
            int q = (int)(val[e] * 16384.0f);
            if (q > 16383) q = 16383;
            tmp[pos] = make_int2(s & 511, dst[e] | (q << 18));
        }
    }
}

// B: per bucket: counting sort by key = local(9b)<<4 | dst_slice(4b).
// Produces per-row edge lists SORTED BY DST SLICE (the gather locality key),
// and 4-byte edge records (dst | q14<<18).
__global__ __launch_bounds__(512)
void passB_kernel(const int2* __restrict__ tmp, const int* __restrict__ bucketBase,
                  int* __restrict__ rowptr, unsigned* __restrict__ edge_s) {
    __shared__ int sdeg[NKEY];   // 32 KB
    __shared__ int cur[NKEY];    // 32 KB
    __shared__ int ttot[512];
    int bkt = blockIdx.x;
    int t = threadIdx.x;                         // 512 threads
    int base = bucketBase[bkt];
    int cntE = bucketBase[bkt + 1] - base;
    for (int k = t; k < NKEY; k += 512) sdeg[k] = 0;
    __syncthreads();
    for (int i = t; i < cntE; i += 512) {
        int2 e = tmp[base + i];
        int key = (e.x << 4) | ((e.y & 0x3FFFF) >> 14);
        atomicAdd(&sdeg[key], 1);
    }
    __syncthreads();
    // exclusive scan over 8192 keys: 16 serial per thread + scan of totals
    int run = 0;
    int k0 = t * 16;
#pragma unroll
    for (int i = 0; i < 16; ++i) { int v = sdeg[k0 + i]; sdeg[k0 + i] = run; run += v; }
    ttot[t] = run;
    __syncthreads();
    for (int o = 1; o < 512; o <<= 1) {          // inclusive Hillis-Steele
        int v = (t >= o) ? ttot[t - o] : 0;
        __syncthreads();
        ttot[t] += v;
        __syncthreads();
    }
    int texcl = ttot[t] - run;                   // exclusive prefix at key t*16
#pragma unroll
    for (int i = 0; i < 16; ++i) { int v = sdeg[k0 + i] + texcl; sdeg[k0 + i] = v; cur[k0 + i] = v; }
    int n = (bkt << 9) + t;                      // row start = slice-0 segment start
    if (n < N_NODES) rowptr[n] = base + texcl;
    __syncthreads();
    for (int i = t; i < cntE; i += 512) {
        int2 e = tmp[base + i];
        int key = (e.x << 4) | ((e.y & 0x3FFFF) >> 14);
        int p = base + atomicAdd(&cur[key], 1);
        edge_s[p] = (unsigned)e.y;
    }
}

// ---------------- propagation layer: 8 threads/node, deep-ILP edge loop ------
// Edge records are 4B (dst | q14<<18), slice-sorted within each row. Edges are
// loaded 4-at-a-time as uint4 (rows peeled to 16B alignment); main loop keeps
// 8 independent 16B gathers in flight per thread.
#define GATHER1(EW)                                                             \
    {                                                                           \
        unsigned ew_ = (EW);                                                    \
        float v_ = ((float)(ew_ >> 18) + 0.5f) * 6.103515625e-5f;               \
        uint4 r_ = *reinterpret_cast<const uint4*>(emb + (long)(ew_ & 0x3FFFF) * EMBED_DIM + c); \
        const __half2* hp_ = reinterpret_cast<const __half2*>(&r_);             \
        float2 f0_ = __half22float2(hp_[0]); float2 f1_ = __half22float2(hp_[1]); \
        float2 f2_ = __half22float2(hp_[2]); float2 f3_ = __half22float2(hp_[3]); \
        a0 += f0_.x * v_; a1 += f0_.y * v_; a2 += f1_.x * v_; a3 += f1_.y * v_; \
        a4 += f2_.x * v_; a5 += f2_.y * v_; a6 += f3_.x * v_; a7 += f3_.y * v_; \
    }

#define ACC8(R, V)                                                              \
    {                                                                           \
        const __half2* hp = reinterpret_cast<const __half2*>(&R);               \
        float2 f0 = __half22float2(hp[0]); float2 f1 = __half22float2(hp[1]);   \
        float2 f2 = __half22float2(hp[2]); float2 f3 = __half22float2(hp[3]);   \
        a0 += f0.x * V; a1 += f0.y * V; a2 += f1.x * V; a3 += f1.y * V;         \
        a4 += f2.x * V; a5 += f2.y * V; a6 += f3.x * V; a7 += f3.y * V;         \
    }

template <bool WRITE_NXT>
__global__ void gather_layer_kernel(const __half* __restrict__ emb, const int* __restrict__ rowptr,
                                    const unsigned* __restrict__ eg, const int* __restrict__ uflag,
                                    __half* __restrict__ outp, float* __restrict__ acc) {
    int tid = blockIdx.x * 256 + threadIdx.x;
    int n = tid >> 3;
    if (n >= N_NODES) return;
    bool needed = (n >= NUM_USERS) || uflag[n];
    if (!WRITE_NXT && !needed) return;            // last layer: only needed rows
    int c = (tid & 7) * 8;                        // dim offset (8 dims/thread)
    int beg = rowptr[n];
    int end = rowptr[n + 1];
    float a0 = 0.f, a1 = 0.f, a2 = 0.f, a3 = 0.f;
    float a4 = 0.f, a5 = 0.f, a6 = 0.f, a7 = 0.f;
    int j = beg;
    while (j < end && (j & 3)) { GATHER1(eg[j]); ++j; }   // peel to 16B align
    for (; j + 8 <= end; j += 8) {
        uint4 ea = *reinterpret_cast<const uint4*>(eg + j);
        uint4 eb = *reinterpret_cast<const uint4*>(eg + j + 4);
        const __half* p0 = emb + (long)(ea.x & 0x3FFFF) * EMBED_DIM + c;
        const __half* p1 = emb + (long)(ea.y & 0x3FFFF) * EMBED_DIM + c;
        const __half* p2 = emb + (long)(ea.z & 0x3FFFF) * EMBED_DIM + c;
        const __half* p3 = emb + (long)(ea.w & 0x3FFFF) * EMBED_DIM + c;
        const __half* p4 = emb + (long)(eb.x & 0x3FFFF) * EMBED_DIM + c;
        const __half* p5 = emb + (long)(eb.y & 0x3FFFF) * EMBED_DIM + c;
        const __half* p6 = emb + (long)(eb.z & 0x3FFFF) * EMBED_DIM + c;
        const __half* p7 = emb + (long)(eb.w & 0x3FFFF) * EMBED_DIM + c;
        uint4 r0 = *reinterpret_cast<const uint4*>(p0);
        uint4 r1 = *reinterpret_cast<const uint4*>(p1);
        uint4 r2 = *reinterpret_cast<const uint4*>(p2);
        uint4 r3 = *reinterpret_cast<const uint4*>(p3);
        uint4 r4 = *reinterpret_cast<const uint4*>(p4);
        uint4 r5 = *reinterpret_cast<const uint4*>(p5);
        uint4 r6 = *reinterpret_cast<const uint4*>(p6);
        uint4 r7 = *reinterpret_cast<const uint4*>(p7);
        float v0 = ((float)(ea.x >> 18) + 0.5f) * 6.103515625e-5f;
        float v1 = ((float)(ea.y >> 18) + 0.5f) * 6.103515625e-5f;
        float v2 = ((float)(ea.z >> 18) + 0.5f) * 6.103515625e-5f;
        float v3 = ((float)(ea.w >> 18) + 0.5f) * 6.103515625e-5f;
        float v4 = ((float)(eb.x >> 18) + 0.5f) * 6.103515625e-5f;
        float v5 = ((float)(eb.y >> 18) + 0.5f) * 6.103515625e-5f;
        float v6 = ((float)(eb.z >> 18) + 0.5f) * 6.103515625e-5f;
        float v7 = ((float)(eb.w >> 18) + 0.5f) * 6.103515625e-5f;
        ACC8(r0, v0) ACC8(r1, v1) ACC8(r2, v2) ACC8(r3, v3)
        ACC8(r4, v4) ACC8(r5, v5) ACC8(r6, v6) ACC8(r7, v7)
    }
    for (; j + 4 <= end; j += 4) {
        uint4 ea = *reinterpret_cast<const uint4*>(eg + j);
        const __half* p0 = emb + (long)(ea.x & 0x3FFFF) * EMBED_DIM + c;
        const __half* p1 = emb + (long)(ea.y & 0x3FFFF) * EMBED_DIM + c;
        const __half* p2 = emb + (long)(ea.z & 0x3FFFF) * EMBED_DIM + c;
        const __half* p3 = emb + (long)(ea.w & 0x3FFFF) * EMBED_DIM + c;
        uint4 r0 = *reinterpret_cast<const uint4*>(p0);
        uint4 r1 = *reinterpret_cast<const uint4*>(p1);
        uint4 r2 = *reinterpret_cast<const uint4*>(p2);
        uint4 r3 = *reinterpret_cast<const uint4*>(p3);
        float v0 = ((float)(ea.x >> 18) + 0.5f) * 6.103515625e-5f;
        float v1 = ((float)(ea.y >> 18) + 0.5f) * 6.103515625e-5f;
        float v2 = ((float)(ea.z >> 18) + 0.5f) * 6.103515625e-5f;
        float v3 = ((float)(ea.w >> 18) + 0.5f) * 6.103515625e-5f;
        ACC8(r0, v0) ACC8(r1, v1) ACC8(r2, v2) ACC8(r3, v3)
    }
    for (; j < end; ++j) GATHER1(eg[j]);

    if (WRITE_NXT) {
        uint4 o;
        __half2* op = reinterpret_cast<__half2*>(&o);
        op[0] = __float22half2_rn(make_float2(a0, a1));
        op[1] = __float22half2_rn(make_float2(a2, a3));
        op[2] = __float22half2_rn(make_float2(a4, a5));
        op[3] = __float22half2_rn(make_float2(a6, a7));
        *reinterpret_cast<uint4*>(outp + (long)n * EMBED_DIM + c) = o;
        if (needed) {
            float* ap = acc + (long)n * EMBED_DIM + c;
            float4 x0 = *reinterpret_cast<float4*>(ap);
            float4 x1 = *reinterpret_cast<float4*>(ap + 4);
            x0.x += a0; x0.y += a1; x0.z += a2; x0.w += a3;
            x1.x += a4; x1.y += a5; x1.z += a6; x1.w += a7;
            *reinterpret_cast<float4*>(ap)     = x0;
            *reinterpret_cast<float4*>(ap + 4) = x1;
        }
    } else {
        // final layer: acc + a is the FINAL value -> write fp16 T16 row directly
        const float* ap = acc + (long)n * EMBED_DIM + c;
        float4 x0 = *reinterpret_cast<const float4*>(ap);
        float4 x1 = *reinterpret_cast<const float4*>(ap + 4);
        uint4 o;
        __half2* op = reinterpret_cast<__half2*>(&o);
        op[0] = __float22half2_rn(make_float2(x0.x + a0, x0.y + a1));
        op[1] = __float22half2_rn(make_float2(x0.z + a2, x0.w + a3));
        op[2] = __float22half2_rn(make_float2(x1.x + a4, x1.y + a5));
        op[3] = __float22half2_rn(make_float2(x1.z + a6, x1.w + a7));
        *reinterpret_cast<uint4*>(outp + (long)n * EMBED_DIM + c) = o;
    }
}

// ---------------- ratings: fp16 MFMA GEMM (fp32 accumulate) ------------------
// A rows gathered from node-indexed T16 via users[]; B rows = T16 item rows.
__global__ __launch_bounds__(256)
void ratings_mfma_kernel(const __half* __restrict__ T16, const int* __restrict__ users,
                         float* __restrict__ out) {
    const int w  = threadIdx.x >> 6;            // wave 0..3
    const int l  = threadIdx.x & 63;
    const int u0 = blockIdx.y * 32 + (w & 1) * 16;
    const int i0 = blockIdx.x * 128 + (w >> 1) * 64;
    const int row = l & 15;
    const int kq  = (l >> 4) * 8;
    const int uid = users[u0 + row];

    f32x4a acc0 = {0.f, 0.f, 0.f, 0.f};
    f32x4a acc1 = {0.f, 0.f, 0.f, 0.f};
    f32x4a acc2 = {0.f, 0.f, 0.f, 0.f};
    f32x4a acc3 = {0.f, 0.f, 0.f, 0.f};

    int ir0 = i0 + 0 * 16 + row; if (ir0 >= NUM_ITEMS) ir0 = NUM_ITEMS - 1;
    int ir1 = i0 + 1 * 16 + row; if (ir1 >= NUM_ITEMS) ir1 = NUM_ITEMS - 1;
    int ir2 = i0 + 2 * 16 + row; if (ir2 >= NUM_ITEMS) ir2 = NUM_ITEMS - 1;
    int ir3 = i0 + 3 * 16 + row; if (ir3 >= NUM_ITEMS) ir3 = NUM_ITEMS - 1;

#pragma unroll
    for (int ks = 0; ks < EMBED_DIM; ks += 32) {
        f16x8 a = *reinterpret_cast<const f16x8*>(T16 + (long)uid * EMBED_DIM + ks + kq);
        f16x8 b0 = *reinterpret_cast<const f16x8*>(T16 + (long)(NUM_USERS + ir0) * EMBED_DIM + ks + kq);
        f16x8 b1 = *reinterpret_cast<const f16x8*>(T16 + (long)(NUM_USERS + ir1) * EMBED_DIM + ks + kq);
        f16x8 b2 = *reinterpret_cast<const f16x8*>(T16 + (long)(NUM_USERS + ir2) * EMBED_DIM + ks + kq);
        f16x8 b3 = *reinterpret_cast<const f16x8*>(T16 + (long)(NUM_USERS + ir3) * EMBED_DIM + ks + kq);
        acc0 = __builtin_amdgcn_mfma_f32_16x16x32_f16(a, b0, acc0, 0, 0, 0);
        acc1 = __builtin_amdgcn_mfma_f32_16x16x32_f16(a, b1, acc1, 0, 0, 0);
        acc2 = __builtin_amdgcn_mfma_f32_16x16x32_f16(a, b2, acc2, 0, 0, 0);
        acc3 = __builtin_amdgcn_mfma_f32_16x16x32_f16(a, b3, acc3, 0, 0, 0);
    }

    const float inv = 1.0f / 16.0f;              // (acc/4)·(acc/4) = acc·acc/16
    const int orow = u0 + (l >> 4) * 4;
    const int colb = l & 15;
#define STORE_FRAG(ACC, C)                                                      \
    {                                                                           \
        int col = i0 + (C) * 16 + colb;                                         \
        if (col < NUM_ITEMS) {                                                  \
            __builtin_nontemporal_store(ACC[0] * inv, out + (long)(orow + 0) * NUM_ITEMS + col); \
            __builtin_nontemporal_store(ACC[1] * inv, out + (long)(orow + 1) * NUM_ITEMS + col); \
            __builtin_nontemporal_store(ACC[2] * inv, out + (long)(orow + 2) * NUM_ITEMS + col); \
            __builtin_nontemporal_store(ACC[3] * inv, out + (long)(orow + 3) * NUM_ITEMS + col); \
        }                                                                       \
    }
    STORE_FRAG(acc0, 0)
    STORE_FRAG(acc1, 1)
    STORE_FRAG(acc2, 2)
    STORE_FRAG(acc3, 3)
#undef STORE_FRAG
}

extern "C" void kernel_launch(void* const* d_in, const int* in_sizes, int n_in,
                              void* d_out, int out_size, void* d_ws, size_t ws_size,
                              hipStream_t stream) {
    const float* ue    = (const float*)d_in[0];
    const float* ie    = (const float*)d_in[1];
    const float* val   = (const float*)d_in[2];
    const int*   src   = (const int*)d_in[3];
    const int*   dst   = (const int*)d_in[4];
    const int*   users = (const int*)d_in[5];
    float* out = (float*)d_out;

    // ws: acc fp32 (38.4 MB) + two fp16 tables (19.2 MB each) + uflag (400 KB)
    const size_t tab = (size_t)N_NODES * EMBED_DIM;
    float*  acc   = (float*)d_ws;
    __half* h0    = (__half*)(acc + tab);
    __half* h1    = h0 + tab;
    int*    uflag = (int*)(h1 + tab);

    // CSR scratch lives in d_out (ratings overwrites all of it at the end)
    char* ob = (char*)d_out;
    unsigned* edge_s  = (unsigned*)(ob);                 // [0,16MB)  final 4B edges
    int2* tmp         = (int2*)(ob + (64u << 20));       // [64,96MB) bucket-partitioned
    int*  hist        = (int*) (ob + (96u << 20));       // 489*293*4 = 573 KB
    int*  off         = (int*) (ob + (98u << 20));       // 573 KB
    int*  bucketTotal = (int*) (ob + (100u << 20));      // 1.2 KB
    int*  bucketBase  = (int*) (ob + (101u << 20));      // 1.2 KB
    int*  rowptr      = (int*) (ob + (102u << 20));      // 600 KB + 4

    clear_uflag_kernel<<<(NUM_USERS + 255) / 256, 256, 0, stream>>>(uflag);
    mark_users_kernel<<<(BATCH + 255) / 256, 256, 0, stream>>>(users, uflag);

    const int totalv = N_NODES * EMBED_DIM / 4;
    init_emb_kernel<<<(totalv + 255) / 256, 256, 0, stream>>>(ue, ie, uflag, acc, (__half2*)h0);

    // ---- CSR build: LDS counting sort, slice-sorted rows, 4B edge records ----
    histA_kernel <<<NBLK_A, 256, 0, stream>>>(src, hist);
    scanA_kernel <<<NBKT, 512, 0, stream>>>(hist, off, bucketTotal);
    scanB_kernel <<<1, 512, 0, stream>>>(bucketTotal, bucketBase, rowptr);
    partA3_kernel<<<NBLK_A, 256, 0, stream>>>(src, dst, val, off, bucketBase, tmp);
    passB_kernel <<<NBKT, 512, 0, stream>>>(tmp, bucketBase, rowptr, edge_s);

    // ---- 3 propagation layers (deep-ILP gather; layer 3 fuses fp16 pack) ----
    const int ggrid = (N_NODES * 8 + 255) / 256;
    gather_layer_kernel<true ><<<ggrid, 256, 0, stream>>>(h0, rowptr, edge_s, uflag, h1, acc);
    gather_layer_kernel<true ><<<ggrid, 256, 0, stream>>>(h1, rowptr, edge_s, uflag, h0, acc);
    gather_layer_kernel<false><<<ggrid, 256, 0, stream>>>(h0, rowptr, edge_s, uflag, h1, acc);

    // ---- ratings GEMM straight from T16 (= h1, written by layer 3) ----
    dim3 rgrid((NUM_ITEMS + 127) / 128, BATCH / 32);
    ratings_mfma_kernel<<<rgrid, 256, 0, stream>>>(h1, users, out);
}